// Round 1
// baseline (169.050 us; speedup 1.0000x reference)
//
#include <hip/hip_runtime.h>
#include <hip/hip_bf16.h>
#include <cstdint>

#define N_NODES 8192
#define DDIM    64
#define DX      128
#define NEDGE   262144
#define BR      128                       // query rows per block (8 waves)
#define BC      64                        // key/value columns per tile
#define SPLITS  8
#define TILES   (N_NODES / BC / SPLITS)   // 16
#define RCAP    64                        // per-row edge bin capacity
#define MSHIFT  66.0f                     // fixed softmax shift: raw scores < 64 always

typedef float f32x16 __attribute__((ext_vector_type(16)));
typedef short short8 __attribute__((ext_vector_type(8)));

__device__ __forceinline__ short f2bf(float f) {
    union { float f; uint32_t u; } v; v.f = f;
    uint32_t u = v.u;
    uint32_t r = (u + 0x7FFFu + ((u >> 16) & 1u)) >> 16;
    return (short)r;
}
__device__ __forceinline__ float bf2f(short s) {
    union { uint32_t u; float f; } v;
    v.u = ((uint32_t)(uint16_t)s) << 16;
    return v.f;
}
__device__ __forceinline__ unsigned cvtpk_bf16(float lo, float hi) {
    unsigned r;
    asm("v_cvt_pk_bf16_f32 %0, %1, %2" : "=v"(r) : "v"(lo), "v"(hi));
    return r;
}
__device__ __forceinline__ float bfsum2(unsigned w) {
    return bf2f((short)(w & 0xFFFFu)) + bf2f((short)(w >> 16));
}
// async global->LDS, 16B per lane; lds base must be wave-uniform (linear dest,
// swizzle applied on the per-lane GLOBAL source address instead)
__device__ __forceinline__ void gload_lds16(const short* g, short* l) {
    __builtin_amdgcn_global_load_lds(
        (const __attribute__((address_space(1))) unsigned int*)g,
        (__attribute__((address_space(3))) unsigned int*)l, 16, 0, 0);
}

// ---- fused prep: [0,2048) X-build, [2048,2304) Y-transpose, [2304,3328) edges
__global__ void cpa_prep_all(const float* __restrict__ mag, const float* __restrict__ phase,
                             const int* __restrict__ ei, const float* __restrict__ ea,
                             const float* __restrict__ W, const float* __restrict__ b,
                             short* __restrict__ Xbf, short* __restrict__ Ybt,
                             float* __restrict__ es, int* __restrict__ cnt,
                             int* __restrict__ keys) {
    __shared__ short tile[64][65];
    __shared__ float wsb[5];
    const int blk = blockIdx.x;
    const int tid = threadIdx.x;
    if (blk < 2048) {
        int idx = blk * 256 + tid;                 // N*64 threads
        int i = idx >> 6, d = idx & 63;
        float m = mag[idx], p = phase[idx];
        Xbf[i * DX + d]      = f2bf(m * __cosf(p));
        Xbf[i * DX + 64 + d] = f2bf(m * __sinf(p));
    } else if (blk < 2304) {
        int bb = blk - 2048;
        int bi = bb >> 1;
        int bc = bb & 1;
        int i0 = bi * 64;
        const float* src = bc ? phase : mag;
        for (int itr = 0; itr < 16; ++itr) {
            int idx = tid + itr * 256;             // 0..4095
            int ii = idx >> 6, cc = idx & 63;
            tile[ii][cc] = f2bf(src[(size_t)(i0 + ii) * 64 + cc]);
        }
        __syncthreads();
        for (int itr = 0; itr < 16; ++itr) {
            int idx = tid + itr * 256;
            int cc = idx >> 6, ii = idx & 63;
            Ybt[(size_t)(bc * 64 + cc) * N_NODES + i0 + ii] = tile[ii][cc];
        }
    } else {
        if (tid < 64) {
            float w0 = W[tid * 4 + 0], w1 = W[tid * 4 + 1];
            float w2 = W[tid * 4 + 2], w3 = W[tid * 4 + 3];
            float bb = b[tid];
            #pragma unroll
            for (int o = 32; o > 0; o >>= 1) {
                w0 += __shfl_down(w0, o);
                w1 += __shfl_down(w1, o);
                w2 += __shfl_down(w2, o);
                w3 += __shfl_down(w3, o);
                bb += __shfl_down(bb, o);
            }
            if (tid == 0) { wsb[0] = w0; wsb[1] = w1; wsb[2] = w2; wsb[3] = w3; wsb[4] = bb; }
        }
        __syncthreads();
        int e = (blk - 2304) * 256 + tid;
        float4 a = *(const float4*)(ea + (size_t)e * 4);
        // store exp(score): walker then multiplies directly (no exp in hot path)
        es[e] = __expf(a.x * wsb[0] + a.y * wsb[1] + a.z * wsb[2] + a.w * wsb[3] + wsb[4]);
        int src = ei[e];
        int dst = ei[NEDGE + e];
        int pos = atomicAdd(&cnt[src], 1);
        if (pos < RCAP) keys[src * RCAP + pos] = (dst << 18) | e;
    }
}

// ---- per-row sort by (dst,e): one wave per row; mark dup dst dead (last-wins)
__global__ __launch_bounds__(256) void cpa_sortrows(const int* __restrict__ cnt,
                                                    int* __restrict__ keys) {
    int row  = blockIdx.x * 4 + (threadIdx.x >> 6);
    int lane = threadIdx.x & 63;
    int len  = min(cnt[row], RCAP);
    int base = row * RCAP;
    int v = (lane < len) ? keys[base + lane] : 0x7FFFFFFF;

    #pragma unroll
    for (int k = 2; k <= 64; k <<= 1) {
        #pragma unroll
        for (int j = k >> 1; j >= 1; j >>= 1) {
            int p = __shfl_xor(v, j);
            bool asc = (lane & k) == 0;
            bool low = (lane & j) == 0;
            v = (low == asc) ? min(v, p) : max(v, p);
        }
    }
    int nxt = __shfl_down(v, 1);
    bool dead = (lane + 1 < len) && ((v >> 18) == (nxt >> 18));
    if (lane < len) keys[base + lane] = v | (dead ? 0x80000000 : 0);
}

// ---- flash attention, swapped-operand 32x32x16 core.
// Wave w = (ig = w>>1, jg = w&1): S' = mfma(A=Xj rows [jg*32,+32), B=Xi rows
// [ig*32,+32)) -> lane col = query i, rows = keys j. Softmax row (exp, edge
// bias, l-sum) fully in registers. P->bf16 A-frags via v_cvt_pk_bf16_f32 +
// lane^32 exchange; jg-partners swap A-frags through 16KB LDS so each wave
// owns a complete O(32 i x 64 f) for f-half fh=jg -> no epilogue O-merge.
// Staging: global_load_lds w/ pre-swizzled source (linear LDS dest), Xj
// double-buffered + issued one tile ahead, Yt issued at top of its own tile
// -> 2 barriers/tile, staging latency hidden under S+softmax.
__global__ __launch_bounds__(512, 4) void cpa_flash(
    const short* __restrict__ Xbf, const short* __restrict__ Ybt,
    const float* __restrict__ es, const int* __restrict__ keys,
    const int* __restrict__ cnt,
    float* __restrict__ lsplit, short* __restrict__ Opart)
{
    __shared__ short XjT[2][64][128];                 // 32 KB, X (cos|sin) j-tile, dbuf
    __shared__ short Yt[128][64];                     // 16 KB, V^T tile: Yt[f][j-local]
    __shared__ unsigned swp[4][2][2][64][4];          // 16 KB, A-frag swap [ig][jg][s][lane][4dw]

    const int tid  = threadIdx.x;
    const int lane = tid & 63;
    const int w    = tid >> 6;
    const int l31  = lane & 31;
    const int lh   = lane >> 5;
    const int ig   = w >> 1;          // query group (32 rows)
    const int jg   = w & 1;           // key half / output f-half

    const int ib = blockIdx.x;
    const int split = blockIdx.y;
    const int i0 = ib * BR;
    const int jstart = split * (N_NODES / SPLITS);

    // Xi B-fragments (registers, loaded once): rows i0+ig*32+l31
    short8 xi[8];
    #pragma unroll
    for (int kf = 0; kf < 8; ++kf)
        xi[kf] = *(const short8*)(Xbf + (size_t)(i0 + ig * 32 + l31) * DX + kf * 16 + lh * 8);

    // staging lane constants (swizzled source offsets; LDS dest linear)
    // Xj: wave w stages tile rows [w*8, w*8+8): 2 calls of 4 rows (16 chunks/row)
    const int xr0 = w * 8 + (lane >> 4);
    const int xc  = lane & 15;
    const int xo0 = (xc ^ (xr0 & 15)) << 3;           // short offset in row
    const int xr1 = xr0 + 4;
    const int xo1 = (xc ^ (xr1 & 15)) << 3;
    // Yt: wave w stages feature rows [w*16, w*16+16): 2 calls of 8 rows (8 chunks/row)
    const int yr0 = w * 16 + (lane >> 3);
    const int yc  = lane & 7;
    const int yo0 = (yc ^ (yr0 & 7)) << 3;
    const int yr1 = yr0 + 8;
    const int yo1 = (yc ^ (yr1 & 7)) << 3;

    // prologue: stage Xj tile 0 into buffer 0
    {
        const short* xsrc = Xbf + (size_t)jstart * DX;
        gload_lds16(xsrc + (size_t)xr0 * DX + xo0, &XjT[0][w * 8][0]);
        gload_lds16(xsrc + (size_t)xr1 * DX + xo1, &XjT[0][w * 8 + 4][0]);
    }

    // walker cursor: all 64 lanes walk row i0+ig*32+l31 (lh halves filter by j parity)
    const int myrow = i0 + ig * 32 + l31;
    int cur  = myrow * RCAP;
    int rend = cur + min(cnt[myrow], RCAP);
    int kcur = 0;
    while (cur < rend) {
        kcur = keys[cur];
        if (((kcur >> 18) & 0x1FFF) >= jstart) break;
        ++cur;
    }

    f32x16 O0, O1;
    float lacc = 0.f;
    #pragma unroll
    for (int r = 0; r < 16; ++r) { O0[r] = 0.f; O1[r] = 0.f; }

    __syncthreads();                  // drains prologue staging (vmcnt 0) + barrier

    int buf = 0;
    for (int tt = 0; tt < TILES; ++tt) {
        const int j0 = jstart + tt * BC;

        // issue current Yt stage + next Xj stage (latency hides under S+softmax)
        gload_lds16(Ybt + (size_t)yr0 * N_NODES + j0 + yo0, &Yt[w * 16][0]);
        gload_lds16(Ybt + (size_t)yr1 * N_NODES + j0 + yo1, &Yt[w * 16 + 8][0]);
        if (tt + 1 < TILES) {
            const short* xsrc = Xbf + (size_t)(j0 + BC) * DX;
            gload_lds16(xsrc + (size_t)xr0 * DX + xo0, &XjT[buf ^ 1][w * 8][0]);
            gload_lds16(xsrc + (size_t)xr1 * DX + xo1, &XjT[buf ^ 1][w * 8 + 4][0]);
        }

        // S' = Xj . Xi^T  (D[m=j][n=i]; lane col = query i)
        f32x16 S;
        #pragma unroll
        for (int r = 0; r < 16; ++r) S[r] = 0.f;
        const int rr = jg * 32 + l31;
        __builtin_amdgcn_s_setprio(1);
        #pragma unroll
        for (int kf = 0; kf < 8; ++kf) {
            const int co = kf * 2 + lh;
            short8 af = *(const short8*)&XjT[buf][rr][(co ^ (rr & 15)) << 3];
            S = __builtin_amdgcn_mfma_f32_32x32x16_bf16(af, xi[kf], S, 0, 0, 0);
        }
        __builtin_amdgcn_s_setprio(0);

        // softmax row in registers: p = exp(S - 66); lane holds 16 j's of query l31
        f32x16 p;
        #pragma unroll
        for (int r = 0; r < 16; ++r) p[r] = __expf(S[r] - MSHIFT);

        // edge bias: consume keys with dst in [wlo, wlo+32); es holds exp(score)
        {
            const int wlo  = j0 + jg * 32;
            const int wend = wlo + 32;
            while (cur < rend) {
                int dst = (kcur >> 18) & 0x1FFF;
                if (dst >= wend) break;
                int kk = kcur;
                ++cur;
                if (cur < rend) kcur = keys[cur];
                int jl = dst - wlo;
                if (kk >= 0 && jl >= 0 && ((jl >> 2) & 1) == lh) {
                    float m = es[kk & 0x3FFFF];
                    int sel = (jl & 3) | ((jl >> 3) << 2);
                    #pragma unroll
                    for (int r = 0; r < 16; ++r)
                        if (r == sel) p[r] *= m;
                }
            }
        }

        // pack P->bf16 A-frags; lane^32 exchange completes each K=16 fragment.
        // frag_s words = {a, a', b, b'} with (a,b) from cvt_pk pairs (m214 T12 pattern)
        unsigned c0 = cvtpk_bf16(p[0], p[1]),   c1 = cvtpk_bf16(p[2], p[3]);
        unsigned c2 = cvtpk_bf16(p[4], p[5]),   c3 = cvtpk_bf16(p[6], p[7]);
        unsigned c4 = cvtpk_bf16(p[8], p[9]),   c5 = cvtpk_bf16(p[10], p[11]);
        unsigned c6 = cvtpk_bf16(p[12], p[13]), c7 = cvtpk_bf16(p[14], p[15]);
        unsigned t0 = __shfl_xor(c0, 32), t2 = __shfl_xor(c2, 32);
        unsigned t1 = __shfl_xor(c1, 32), t3 = __shfl_xor(c3, 32);
        unsigned t4 = __shfl_xor(c4, 32), t6 = __shfl_xor(c6, 32);
        unsigned t5 = __shfl_xor(c5, 32), t7 = __shfl_xor(c7, 32);
        union FU { unsigned u[4]; short8 s; int4 v; };
        FU F0, F1;
        F0.u[0] = lh ? t2 : c0;  F0.u[1] = lh ? t3 : c1;   // k 0..3  (of this K=16)
        F0.u[2] = lh ? c2 : t0;  F0.u[3] = lh ? c3 : t1;   // k 4..7
        F1.u[0] = lh ? t6 : c4;  F1.u[1] = lh ? t7 : c5;
        F1.u[2] = lh ? c6 : t4;  F1.u[3] = lh ? c7 : t5;

        // l accumulation from the exact bf16 values PV will use (lane pair
        // (l,l^32) together covers all 32 j of this wave's window)
        lacc += bfsum2(F0.u[0]) + bfsum2(F0.u[1]) + bfsum2(F0.u[2]) + bfsum2(F0.u[3]);
        lacc += bfsum2(F1.u[0]) + bfsum2(F1.u[1]) + bfsum2(F1.u[2]) + bfsum2(F1.u[3]);

        // publish own A-frags to jg-partner
        *(int4*)&swp[ig][jg][0][lane][0] = F0.v;
        *(int4*)&swp[ig][jg][1][lane][0] = F1.v;

        __syncthreads();   // B2: Yt staged + drained; A-frags visible

        short8 own0 = F0.s, own1 = F1.s;
        short8 oth0 = *(const short8*)&swp[ig][jg ^ 1][0][lane][0];
        short8 oth1 = *(const short8*)&swp[ig][jg ^ 1][1][lane][0];

        // PV: O[i][f], f-half fh=jg, K = full 64 j (own window + partner window)
        const int fA = jg * 64 + l31;
        const int fB = fA + 32;
        __builtin_amdgcn_s_setprio(1);
        #pragma unroll
        for (int sl = 0; sl < 2; ++sl) {
            short8 ao = sl ? own1 : own0;
            short8 at = sl ? oth1 : oth0;
            const int co_o = jg * 4 + sl * 2 + lh;          // own j-window chunk
            const int co_t = (jg ^ 1) * 4 + sl * 2 + lh;    // partner j-window chunk
            short8 b0o = *(const short8*)&Yt[fA][(co_o ^ (fA & 7)) << 3];
            short8 b0t = *(const short8*)&Yt[fA][(co_t ^ (fA & 7)) << 3];
            short8 b1o = *(const short8*)&Yt[fB][(co_o ^ (fB & 7)) << 3];
            short8 b1t = *(const short8*)&Yt[fB][(co_t ^ (fB & 7)) << 3];
            O0 = __builtin_amdgcn_mfma_f32_32x32x16_bf16(ao, b0o, O0, 0, 0, 0);
            O0 = __builtin_amdgcn_mfma_f32_32x32x16_bf16(at, b0t, O0, 0, 0, 0);
            O1 = __builtin_amdgcn_mfma_f32_32x32x16_bf16(ao, b1o, O1, 0, 0, 0);
            O1 = __builtin_amdgcn_mfma_f32_32x32x16_bf16(at, b1t, O1, 0, 0, 0);
        }
        __builtin_amdgcn_s_setprio(0);

        __syncthreads();   // WAR: LDS reads done before next tile's staging/swap writes
        buf ^= 1;
    }

    // epilogue: l cross-half + cross-jg merge (reuse swp as scratch), O write
    lacc += __shfl_xor(lacc, 32);
    float* lmbuf = (float*)&swp[0][0][0][0][0];
    if (jg == 1 && lane < 32) lmbuf[ig * 32 + l31] = lacc;
    __syncthreads();
    if (jg == 0 && lane < 32)
        lsplit[(size_t)split * N_NODES + i0 + ig * 32 + l31] = lacc + lmbuf[ig * 32 + l31];

    #pragma unroll
    for (int r = 0; r < 16; ++r) {
        int row = ig * 32 + 4 * lh + (r & 3) + 8 * (r >> 2);
        size_t base = ((size_t)split * N_NODES + i0 + row) * DX;
        Opart[base + jg * 64 + l31]      = f2bf(O0[r]);
        Opart[base + jg * 64 + 32 + l31] = f2bf(O1[r]);
    }
}

// ---- merge splits (plain sums) + normalize + write [new_mag | new_phase]
__global__ void cpa_merge(const float* __restrict__ lsplit, const short* __restrict__ Opart,
                          float* __restrict__ out) {
    int gid = blockIdx.x * 256 + threadIdx.x;   // N*128 threads
    int i = gid >> 7;
    int c = gid & 127;
    float den = 0.f, num = 0.f;
    #pragma unroll
    for (int s = 0; s < SPLITS; ++s) {
        den += lsplit[(size_t)s * N_NODES + i];
        num += bf2f(Opart[((size_t)s * N_NODES + i) * DX + c]);
    }
    float val = num / den;
    if (c < 64) out[(size_t)i * 64 + c] = val;
    else        out[(size_t)N_NODES * 64 + (size_t)i * 64 + (c - 64)] = val;
}

extern "C" void kernel_launch(void* const* d_in, const int* in_sizes, int n_in,
                              void* d_out, int out_size, void* d_ws, size_t ws_size,
                              hipStream_t stream)
{
    const float* mag   = (const float*)d_in[0];
    const float* phase = (const float*)d_in[1];
    const int*   ei    = (const int*)d_in[2];     // edge_index [2][E] (int32 per harness)
    const float* ea    = (const float*)d_in[3];
    const float* W     = (const float*)d_in[4];
    const float* b     = (const float*)d_in[5];
    float* out = (float*)d_out;

    char* ws = (char*)d_ws;
    short* Xbf    = (short*)(ws + 0);               // 2 MB
    short* Ybt    = (short*)(ws + 2097152);         // 2 MB
    float* es     = (float*)(ws + 4194304);         // 1 MB (exp(edge score))
    int*   keys   = (int*)  (ws + 5242880);         // 2 MB (8192 rows x 64 bins)
    int*   cnt    = (int*)  (ws + 7340032);         // 32 KB
    float* lsplit = (float*)(ws + 7373056);         // 256 KB (8 splits)
    short* Opart  = (short*)(ws + 7635200);         // 16 MB (bf16, 8 splits)

    hipMemsetAsync(cnt, 0, N_NODES * sizeof(int), stream);
    cpa_prep_all<<<2048 + 256 + NEDGE / 256, 256, 0, stream>>>(mag, phase, ei, ea, W, b,
                                                               Xbf, Ybt, es, cnt, keys);
    cpa_sortrows<<<N_NODES / 4, 256, 0, stream>>>(cnt, keys);
    cpa_flash<<<dim3(N_NODES / BR, SPLITS), 512, 0, stream>>>(Xbf, Ybt, es, keys, cnt,
                                                              lsplit, Opart);
    cpa_merge<<<N_NODES * DX / 256, 256, 0, stream>>>(lsplit, Opart, out);
}